// Round 4
// baseline (126.061 us; speedup 1.0000x reference)
//
#include <hip/hip_runtime.h>
#include <math.h>

#define M_  2
#define B_  256
#define L_  1024
#define K_  4
#define S_  20
#define NR_ 100
#define NTERM 7   // Taylor terms T_1..T_7 ; ||mu*Q||inf <= 0.13 -> rem ~2e-11

__device__ __forceinline__ float softplusf(float x) {
    return x > 20.0f ? x : log1pf(expf(x));
}

// ---------------------------------------------------------------------------
// Kernel 1: per (m,k), compute normalized Q, store T_n = Q^n/n!, n=1..NTERM.
// 8 blocks; 512 threads, 400 active.
// ---------------------------------------------------------------------------
__global__ __launch_bounds__(512)
void qpow_kernel(const float* __restrict__ exch,   // (M,K,S,S)
                 const float* __restrict__ equil,  // (M,K,S)
                 float*       __restrict__ Qpow)   // (M,K,NTERM,400)
{
    __shared__ float sQ[400];
    __shared__ float sT[2][400];
    __shared__ float sRow[20];

    const int blk = blockIdx.x;          // mm*K_ + kk
    const int kk = blk % K_;
    const int mm = blk / K_;
    const int tid = threadIdx.x;
    const bool act = tid < 400;
    const int i = tid / 20;
    const int j = tid - i * 20;

    float p[20];
    float Q0 = 0.0f, rowsum = 0.0f;

    if (act) {
        const float* eq = equil + (mm * K_ + kk) * S_;
        float mx = eq[0];
        #pragma unroll
        for (int z = 1; z < 20; ++z) mx = fmaxf(mx, eq[z]);
        float s = 0.0f;
        #pragma unroll
        for (int z = 0; z < 20; ++z) { p[z] = expf(eq[z] - mx); s += p[z]; }
        const float inv = 1.0f / s;
        #pragma unroll
        for (int z = 0; z < 20; ++z) p[z] *= inv;

        const float* Kx = exch + (mm * K_ + kk) * S_ * S_;
        float R = (i == j) ? 0.0f : softplusf(0.5f * (Kx[i * 20 + j] + Kx[j * 20 + i]));
        Q0 = R * p[j];
        sQ[tid] = Q0;
    }
    __syncthreads();

    if (act) {
        rowsum = 0.0f;
        #pragma unroll
        for (int z = 0; z < 20; ++z) rowsum += sQ[i * 20 + z];
        if (j == 0) sRow[i] = rowsum;
    }
    __syncthreads();

    float* Tout = Qpow + (size_t)blk * (NTERM * 400);
    if (act) {
        float mue = 0.0f;
        #pragma unroll
        for (int z = 0; z < 20; ++z) mue += p[z] * sRow[z];
        float q = (Q0 - ((i == j) ? rowsum : 0.0f)) / fmaxf(mue, 1e-16f);
        sQ[tid] = q;
        sT[0][tid] = q;
        Tout[tid] = q;       // T_1 = Q
    }
    __syncthreads();

    int cur = 0;
    for (int n = 2; n <= NTERM; ++n) {
        if (act) {
            float acc = 0.0f;
            #pragma unroll
            for (int z = 0; z < 20; ++z) acc += sT[cur][i * 20 + z] * sQ[z * 20 + j];
            acc /= (float)n;
            sT[cur ^ 1][tid] = acc;
            Tout[(n - 1) * 400 + tid] = acc;   // T_n = Q^n / n!
        }
        __syncthreads();
        cur ^= 1;
    }
}

// ---------------------------------------------------------------------------
// Kernel 2: P[m,r,k] = I + sum_n mu^n T_n  (linear combo, no matmuls).
// 800 blocks x 512 threads (400 active), no LDS, no barriers.
// ---------------------------------------------------------------------------
__global__ __launch_bounds__(512)
void pbuild_kernel(const float* __restrict__ Qpow,  // (M,K,NTERM,400)
                   const float* __restrict__ tauk,  // (M,NR)
                   const float* __restrict__ pmrk,  // (M,K)
                   float*       __restrict__ Pws)   // (M,NR,K,400)
{
    const int blk = blockIdx.x;          // mm*NR*K + rr*K + kk
    const int kk = blk % K_;
    const int rr = (blk / K_) % NR_;
    const int mm = blk / (K_ * NR_);
    const int tid = threadIdx.x;
    if (tid >= 400) return;

    const float mu = softplusf(tauk[mm * NR_ + rr]) * softplusf(pmrk[mm * K_ + kk]);
    const float* T = Qpow + ((size_t)(mm * K_ + kk) * NTERM) * 400 + tid;

    float acc = (tid % 21 == 0) ? 1.0f : 0.0f;   // identity
    float mp = mu;
    #pragma unroll
    for (int n = 0; n < NTERM; ++n) { acc = fmaf(mp, T[n * 400], acc); mp *= mu; }
    Pws[(size_t)blk * 400 + tid] = acc;
}

// ---------------------------------------------------------------------------
// Kernel 3: anc[m,b,l,k*20+s] = sum_z inputs[m,b,l,z] * P[m,ridx[m,b],k,z,s]
// One block per (mb, 64-row chunk): 8192 blocks. 320 threads = 16 row-groups
// x 20 col-tasks; each thread does 4 rows (stride 16) x 4 contiguous cols.
// acc = 16 VGPR; launch_bounds(...,8) pins the <=64-VGPR tier -> 30 waves/CU.
// ---------------------------------------------------------------------------
#define RPB 64
#define TPB 320

__device__ __forceinline__ void fma4(float4& a, float s, const float4& p) {
    a.x = fmaf(s, p.x, a.x);
    a.y = fmaf(s, p.y, a.y);
    a.z = fmaf(s, p.z, a.z);
    a.w = fmaf(s, p.w, a.w);
}

__global__ __launch_bounds__(TPB, 8)
void einsum_kernel(const float* __restrict__ inp,  // (M,B,L,S)
                   const float* __restrict__ Pws,  // (M,NR,K,400)
                   const int*   __restrict__ ridx, // (M,B)
                   float*       __restrict__ out)  // (M,B,L,K*S)
{
    __shared__ float Pl[K_ * 400];        // 1600 floats
    __shared__ float inL[RPB * 20];       // 1280 floats

    const int bx    = blockIdx.x;
    const int chunk = bx & 15;            // L_/RPB = 16 chunks
    const int mb    = bx >> 4;            // 0..511
    const int mm    = mb >> 8;
    const int tid   = threadIdx.x;

    const int r = ridx[mb];               // block-uniform

    // stage P[m,r] (1600 floats) and input chunk (1280 floats), float4s
    {
        const float4* Psrc = (const float4*)(Pws + ((size_t)(mm * NR_ + r) * K_) * 400);
        float4* Pd = (float4*)Pl;
        Pd[tid] = Psrc[tid];
        if (tid < 80) Pd[320 + tid] = Psrc[320 + tid];

        const float4* Isrc = (const float4*)(inp + ((size_t)mb * L_ + chunk * RPB) * 20);
        ((float4*)inL)[tid] = Isrc[tid];  // 320 float4 = 64 rows
    }
    __syncthreads();

    const int t  = tid % 20;    // output column group: 4 cols at t*4
    const int rg = tid / 20;    // 0..15 row group
    const int k  = t / 5;
    const int s0 = (t - k * 5) * 4;
    const float* Pk = Pl + k * 400 + s0;

    float4 acc[4];
    #pragma unroll
    for (int r4 = 0; r4 < 4; ++r4) acc[r4] = make_float4(0.f, 0.f, 0.f, 0.f);

    #pragma unroll
    for (int z4 = 0; z4 < 5; ++z4) {
        const float4 p0 = *(const float4*)(Pk + (z4 * 4 + 0) * 20);
        const float4 p1 = *(const float4*)(Pk + (z4 * 4 + 1) * 20);
        const float4 p2 = *(const float4*)(Pk + (z4 * 4 + 2) * 20);
        const float4 p3 = *(const float4*)(Pk + (z4 * 4 + 3) * 20);
        #pragma unroll
        for (int r4 = 0; r4 < 4; ++r4) {
            const int l = rg + r4 * 16;
            const float4 av = *(const float4*)(inL + l * 20 + z4 * 4);
            fma4(acc[r4], av.x, p0);
            fma4(acc[r4], av.y, p1);
            fma4(acc[r4], av.z, p2);
            fma4(acc[r4], av.w, p3);
        }
    }

    float* ob = out + ((size_t)mb * L_ + chunk * RPB) * 80;
    #pragma unroll
    for (int r4 = 0; r4 < 4; ++r4) {
        const int l = rg + r4 * 16;
        *(float4*)(ob + l * 80 + t * 4) = acc[r4];
    }
}

// ---------------------------------------------------------------------------
extern "C" void kernel_launch(void* const* d_in, const int* in_sizes, int n_in,
                              void* d_out, int out_size, void* d_ws, size_t ws_size,
                              hipStream_t stream) {
    const float* inp   = (const float*)d_in[0];  // (M,B,L,S)
    const float* tauk  = (const float*)d_in[1];  // (M,NR)
    const float* exch  = (const float*)d_in[2];  // (M,K,S,S)
    const float* equil = (const float*)d_in[3];  // (M,K,S)
    const float* pmrk  = (const float*)d_in[4];  // (M,K)
    const int*   ridx  = (const int*)d_in[5];    // (M,B)
    float* outp = (float*)d_out;

    float* Qpow = (float*)d_ws;                          // M*K*NTERM*400*4 = 89.6 KB
    float* Pws  = Qpow + (size_t)M_ * K_ * NTERM * 400;  // M*NR*K*400*4 = 1.28 MB

    qpow_kernel<<<M_ * K_, 512, 0, stream>>>(exch, equil, Qpow);
    pbuild_kernel<<<M_ * NR_ * K_, 512, 0, stream>>>(Qpow, tauk, pmrk, Pws);
    einsum_kernel<<<M_ * B_ * (L_ / RPB), TPB, 0, stream>>>(inp, Pws, ridx, outp);
}

// Round 5
// 60.670 us; speedup vs baseline: 2.0778x; 2.0778x over previous
//
#include <hip/hip_runtime.h>
#include <math.h>

#define M_  2
#define B_  256
#define L_  1024
#define K_  4
#define S_  20
#define NR_ 100
#define NTERM 7   // Taylor terms T_1..T_7 ; ||mu*Q||inf <= 0.13 -> rem ~2e-11

// einsum geometry
#define SPAN  512            // rows per block
#define CHUNK 128            // rows per chunk
#define NCH   (SPAN / CHUNK) // 4
#define TPB   320

__device__ __forceinline__ float softplusf(float x) {
    return x > 20.0f ? x : log1pf(expf(x));
}

// ---------------------------------------------------------------------------
// Kernel 1: per (m,k), compute normalized Q, store T_n = Q^n/n!, n=1..NTERM.
// ---------------------------------------------------------------------------
__global__ __launch_bounds__(512)
void qpow_kernel(const float* __restrict__ exch,   // (M,K,S,S)
                 const float* __restrict__ equil,  // (M,K,S)
                 float*       __restrict__ Qpow)   // (M,K,NTERM,400)
{
    __shared__ float sQ[400];
    __shared__ float sT[2][400];
    __shared__ float sRow[20];

    const int blk = blockIdx.x;          // mm*K_ + kk
    const int kk = blk % K_;
    const int mm = blk / K_;
    const int tid = threadIdx.x;
    const bool act = tid < 400;
    const int i = tid / 20;
    const int j = tid - i * 20;

    float p[20];
    float Q0 = 0.0f, rowsum = 0.0f;

    if (act) {
        const float* eq = equil + (mm * K_ + kk) * S_;
        float mx = eq[0];
        #pragma unroll
        for (int z = 1; z < 20; ++z) mx = fmaxf(mx, eq[z]);
        float s = 0.0f;
        #pragma unroll
        for (int z = 0; z < 20; ++z) { p[z] = expf(eq[z] - mx); s += p[z]; }
        const float inv = 1.0f / s;
        #pragma unroll
        for (int z = 0; z < 20; ++z) p[z] *= inv;

        const float* Kx = exch + (mm * K_ + kk) * S_ * S_;
        float R = (i == j) ? 0.0f : softplusf(0.5f * (Kx[i * 20 + j] + Kx[j * 20 + i]));
        Q0 = R * p[j];
        sQ[tid] = Q0;
    }
    __syncthreads();

    if (act) {
        rowsum = 0.0f;
        #pragma unroll
        for (int z = 0; z < 20; ++z) rowsum += sQ[i * 20 + z];
        if (j == 0) sRow[i] = rowsum;
    }
    __syncthreads();

    float* Tout = Qpow + (size_t)blk * (NTERM * 400);
    if (act) {
        float mue = 0.0f;
        #pragma unroll
        for (int z = 0; z < 20; ++z) mue += p[z] * sRow[z];
        float q = (Q0 - ((i == j) ? rowsum : 0.0f)) / fmaxf(mue, 1e-16f);
        sQ[tid] = q;
        sT[0][tid] = q;
        Tout[tid] = q;       // T_1 = Q
    }
    __syncthreads();

    int cur = 0;
    for (int n = 2; n <= NTERM; ++n) {
        if (act) {
            float acc = 0.0f;
            #pragma unroll
            for (int z = 0; z < 20; ++z) acc += sT[cur][i * 20 + z] * sQ[z * 20 + j];
            acc /= (float)n;
            sT[cur ^ 1][tid] = acc;
            Tout[(n - 1) * 400 + tid] = acc;   // T_n = Q^n / n!
        }
        __syncthreads();
        cur ^= 1;
    }
}

// ---------------------------------------------------------------------------
// Kernel 2: P[m,r,k] = I + sum_n mu^n T_n  (linear combo, no matmuls).
// ---------------------------------------------------------------------------
__global__ __launch_bounds__(512)
void pbuild_kernel(const float* __restrict__ Qpow,  // (M,K,NTERM,400)
                   const float* __restrict__ tauk,  // (M,NR)
                   const float* __restrict__ pmrk,  // (M,K)
                   float*       __restrict__ Pws)   // (M,NR,K,400)
{
    const int blk = blockIdx.x;          // mm*NR*K + rr*K + kk
    const int kk = blk % K_;
    const int rr = (blk / K_) % NR_;
    const int mm = blk / (K_ * NR_);
    const int tid = threadIdx.x;
    if (tid >= 400) return;

    const float mu = softplusf(tauk[mm * NR_ + rr]) * softplusf(pmrk[mm * K_ + kk]);
    const float* T = Qpow + ((size_t)(mm * K_ + kk) * NTERM) * 400 + tid;

    float acc = (tid % 21 == 0) ? 1.0f : 0.0f;   // identity
    float mp = mu;
    #pragma unroll
    for (int n = 0; n < NTERM; ++n) { acc = fmaf(mp, T[n * 400], acc); mp *= mu; }
    Pws[(size_t)blk * 400 + tid] = acc;
}

// ---------------------------------------------------------------------------
// Kernel 3: anc[m,b,l,k*20+s] = sum_z inputs[m,b,l,z] * P[m,ridx[m,b],k,z,s]
// One block per (mb, 512-row half): 1024 blocks, 320 threads (5 waves).
// P staged ONCE per block; input double-buffered via global_load_lds(16B),
// chunk c+1 loads issued after the barrier retiring buffer (c+1)&1, so they
// overlap chunk c's compute+store. Natural VGPR alloc (no min-waves bound).
// ---------------------------------------------------------------------------
__device__ __forceinline__ void fma4(float4& a, float s, const float4& p) {
    a.x = fmaf(s, p.x, a.x);
    a.y = fmaf(s, p.y, a.y);
    a.z = fmaf(s, p.z, a.z);
    a.w = fmaf(s, p.w, a.w);
}

__device__ __forceinline__ void stage_chunk_async(const char* gsrc, char* ldsbase,
                                                  int wave, int lane) {
    // 10240 B per chunk = 10 x 1KB wave-chunks; 5 waves issue 2 each.
    #pragma unroll
    for (int q = 0; q < 2; ++q) {
        const int boff = (wave * 2 + q) * 1024;
        __builtin_amdgcn_global_load_lds(
            (const __attribute__((address_space(1))) void*)(gsrc + boff + lane * 16),
            (__attribute__((address_space(3))) void*)(ldsbase + boff),
            16, 0, 0);
    }
}

__global__ __launch_bounds__(TPB)
void einsum_kernel(const float* __restrict__ inp,  // (M,B,L,S)
                   const float* __restrict__ Pws,  // (M,NR,K,400)
                   const int*   __restrict__ ridx, // (M,B)
                   float*       __restrict__ out)  // (M,B,L,K*S)
{
    __shared__ float Pl[K_ * 400];            // 6400 B
    __shared__ float inL[2][CHUNK * 20];      // 2 x 10240 B

    const int bx   = blockIdx.x;
    const int half = bx & 1;                  // L_/SPAN = 2
    const int mb   = bx >> 1;                 // 0..511
    const int mm   = mb >> 8;
    const int tid  = threadIdx.x;
    const int wave = tid >> 6;
    const int lane = tid & 63;

    const int r = ridx[mb];                   // block-uniform

    const size_t row0 = (size_t)mb * L_ + (size_t)half * SPAN;
    const char* gin = (const char*)(inp + row0 * 20);

    // issue chunk 0 async loads, then stage P (both drained at first barrier)
    stage_chunk_async(gin, (char*)&inL[0][0], wave, lane);
    {
        const float4* Psrc = (const float4*)(Pws + ((size_t)(mm * NR_ + r) * K_) * 400);
        float4* Pd = (float4*)Pl;
        Pd[tid] = Psrc[tid];
        if (tid < 80) Pd[320 + tid] = Psrc[320 + tid];
    }

    const int t  = tid % 20;    // output column group: 4 cols at t*4
    const int rg = tid / 20;    // 0..15 row group
    const int k  = t / 5;
    const int s0 = (t - k * 5) * 4;
    const float* Pk = Pl + k * 400 + s0;

    for (int c = 0; c < NCH; ++c) {
        asm volatile("s_waitcnt vmcnt(0)" ::: "memory");
        __syncthreads();    // chunk c (and P on c==0) ready; buffer (c+1)&1 retired

        if (c + 1 < NCH)
            stage_chunk_async(gin + (c + 1) * (CHUNK * 80),
                              (char*)&inL[(c + 1) & 1][0], wave, lane);

        const float* inb = &inL[c & 1][0];

        float4 acc[8];
        #pragma unroll
        for (int r8 = 0; r8 < 8; ++r8) acc[r8] = make_float4(0.f, 0.f, 0.f, 0.f);

        #pragma unroll
        for (int z4 = 0; z4 < 5; ++z4) {
            const float4 p0 = *(const float4*)(Pk + (z4 * 4 + 0) * 20);
            const float4 p1 = *(const float4*)(Pk + (z4 * 4 + 1) * 20);
            const float4 p2 = *(const float4*)(Pk + (z4 * 4 + 2) * 20);
            const float4 p3 = *(const float4*)(Pk + (z4 * 4 + 3) * 20);
            #pragma unroll
            for (int r8 = 0; r8 < 8; ++r8) {
                const int l = rg + r8 * 16;
                const float4 av = *(const float4*)(inb + l * 20 + z4 * 4);
                fma4(acc[r8], av.x, p0);
                fma4(acc[r8], av.y, p1);
                fma4(acc[r8], av.z, p2);
                fma4(acc[r8], av.w, p3);
            }
        }

        float* ob = out + (row0 + (size_t)c * CHUNK) * 80;
        #pragma unroll
        for (int r8 = 0; r8 < 8; ++r8) {
            const int l = rg + r8 * 16;
            *(float4*)(ob + l * 80 + t * 4) = acc[r8];
        }
    }
}

// ---------------------------------------------------------------------------
extern "C" void kernel_launch(void* const* d_in, const int* in_sizes, int n_in,
                              void* d_out, int out_size, void* d_ws, size_t ws_size,
                              hipStream_t stream) {
    const float* inp   = (const float*)d_in[0];  // (M,B,L,S)
    const float* tauk  = (const float*)d_in[1];  // (M,NR)
    const float* exch  = (const float*)d_in[2];  // (M,K,S,S)
    const float* equil = (const float*)d_in[3];  // (M,K,S)
    const float* pmrk  = (const float*)d_in[4];  // (M,K)
    const int*   ridx  = (const int*)d_in[5];    // (M,B)
    float* outp = (float*)d_out;

    float* Qpow = (float*)d_ws;                          // 89.6 KB
    float* Pws  = Qpow + (size_t)M_ * K_ * NTERM * 400;  // 1.28 MB

    qpow_kernel<<<M_ * K_, 512, 0, stream>>>(exch, equil, Qpow);
    pbuild_kernel<<<M_ * NR_ * K_, 512, 0, stream>>>(Qpow, tauk, pmrk, Pws);
    einsum_kernel<<<M_ * B_ * (L_ / SPAN), TPB, 0, stream>>>(inp, Pws, ridx, outp);
}